// Round 3
// baseline (550.842 us; speedup 1.0000x reference)
//
#include <hip/hip_runtime.h>
#include <math.h>

// Problem constants
#define NSPK  65536
#define HID   1024
#define DUP   2048
#define CAT   3072
#define LN_EPS 1e-5f

typedef float f4 __attribute__((ext_vector_type(4)));

constexpr int NB = 256;   // mega-kernel grid: 1 block/CU, co-residency guaranteed

// Workspace layout (floats):
#define WS_QUERY   0
#define WS_CONTEXT 1024
#define WS_H       2048
#define WS_O       4096
#define WS_PM      5120            // 256 partial maxes
#define WS_PL      5376            // 256 partial denoms
#define WS_CNT     5632            // barrier counter (int)
#define WS_PC      8192            // 256*1024 context partials (1 MiB)

__device__ __forceinline__ float wave_sum64(float d) {
#pragma unroll
  for (int s = 32; s > 0; s >>= 1) d += __shfl_xor(d, s, 64);
  return d;
}
__device__ __forceinline__ float wave_max64(float d) {
#pragma unroll
  for (int s = 32; s > 0; s >>= 1) d = fmaxf(d, __shfl_xor(d, s, 64));
  return d;
}

// Device-scope grid barrier (the pattern grid.sync() lowers to).
// Graph-capture safe: pure device code, counter re-zeroed each iteration by kA.
__device__ __forceinline__ void gbar_arrive(int* cnt) {
  __syncthreads();                 // all waves' stores drained (vmcnt 0) at barrier
  if (threadIdx.x == 0) {
    __threadfence();               // release: write back this XCD's L2
    atomicAdd(cnt, 1);             // device-scope
  }
}
__device__ __forceinline__ void gbar_wait(int* cnt, int target) {
  if (threadIdx.x == 0) {
    while (__hip_atomic_load(cnt, __ATOMIC_ACQUIRE, __HIP_MEMORY_SCOPE_AGENT) < target)
      __builtin_amdgcn_s_sleep(2);
    __threadfence();               // acquire: invalidate stale L1/L2
  }
  __syncthreads();
}

// ---------------------------------------------------------------------------
// kA: query = W_attn @ u_t (one wave per row) + barrier-counter init.
__global__ __launch_bounds__(256) void kA_query(
    const float* __restrict__ W_attn, const float* __restrict__ u_t,
    float* __restrict__ query, int* __restrict__ cnt) {
  if (blockIdx.x == 0 && threadIdx.x == 0) *cnt = 0;
  const int lane = threadIdx.x & 63;
  const int wv = threadIdx.x >> 6;
  const int row = blockIdx.x * 4 + wv;
  const float* rp = W_attn + (size_t)row * HID;
  float d = 0.f;
#pragma unroll
  for (int i = 0; i < 4; ++i) {
    f4 v = *(const f4*)(rp + i * 256 + lane * 4);
    f4 u = *(const f4*)(u_t + i * 256 + lane * 4);
    f4 p = v * u;
    d += p.x + p.y + p.z + p.w;
  }
  d = wave_sum64(d);
  if (lane == 0) query[row] = d;
}

// ---------------------------------------------------------------------------
// kB: mega-kernel. 256 blocks x 1024 threads (16 waves). Phases P1..P5
// separated by software grid barriers.
__global__ __launch_bounds__(1024, 4) void kB_fused(
    const float* __restrict__ u_t, const float* __restrict__ emb,
    const float* __restrict__ W1, const float* __restrict__ b1,
    const float* __restrict__ W2, const float* __restrict__ b2,
    const float* __restrict__ gamma, const float* __restrict__ beta,
    const int* __restrict__ s_i_p, float* __restrict__ out,
    float* __restrict__ ws) {
  float* query   = ws + WS_QUERY;
  float* context = ws + WS_CONTEXT;
  float* h       = ws + WS_H;
  float* o       = ws + WS_O;
  float* pm      = ws + WS_PM;
  float* pl      = ws + WS_PL;
  float* pc      = ws + WS_PC;
  int*   cnt     = (int*)(ws + WS_CNT);

  const int tid  = threadIdx.x;
  const int lane = tid & 63;
  const int wv   = tid >> 6;          // 0..15
  const int bid  = blockIdx.x;

  __shared__ float sm[16], sl[16], sh[16], sred[16];
  __shared__ f4 sc[16][256];          // 64 KiB
  __shared__ float sw[256];
  __shared__ float sacc[1024];        // 4 KiB

  // ---- P1: streaming scan of the bank (copy + logits + context partials).
  // 256 blocks x 16 waves x 16 rows = 65536 rows. Same per-wave structure
  // as the validated K1 (reg double-buffer, NT loads/stores, defer-max).
  {
    const int gw = bid * 16 + wv;     // 0..4095
    const int col = lane * 4;
    f4 q0 = *(const f4*)(query + 0 * 256 + col);
    f4 q1 = *(const f4*)(query + 1 * 256 + col);
    f4 q2 = *(const f4*)(query + 2 * 256 + col);
    f4 q3 = *(const f4*)(query + 3 * 256 + col);

    float m = -INFINITY, l = 0.f;
    f4 c0 = {0.f, 0.f, 0.f, 0.f}, c1 = c0, c2 = c0, c3 = c0;

    const int row0 = gw * 16;
    const float* rp0 = emb + (size_t)row0 * HID + col;
    f4 v0 = __builtin_nontemporal_load((const f4*)(rp0 + 0 * 256));
    f4 v1 = __builtin_nontemporal_load((const f4*)(rp0 + 1 * 256));
    f4 v2 = __builtin_nontemporal_load((const f4*)(rp0 + 2 * 256));
    f4 v3 = __builtin_nontemporal_load((const f4*)(rp0 + 3 * 256));

    for (int r = 0; r < 16; ++r) {
      f4 n0, n1, n2, n3;
      if (r < 15) {
        const float* np = emb + (size_t)(row0 + r + 1) * HID + col;
        n0 = __builtin_nontemporal_load((const f4*)(np + 0 * 256));
        n1 = __builtin_nontemporal_load((const f4*)(np + 1 * 256));
        n2 = __builtin_nontemporal_load((const f4*)(np + 2 * 256));
        n3 = __builtin_nontemporal_load((const f4*)(np + 3 * 256));
      } else {
        n0 = v0; n1 = v1; n2 = v2; n3 = v3;
      }
      float* op = out + (size_t)(row0 + r) * HID + col;
      __builtin_nontemporal_store(v0, (f4*)(op + 0 * 256));
      __builtin_nontemporal_store(v1, (f4*)(op + 1 * 256));
      __builtin_nontemporal_store(v2, (f4*)(op + 2 * 256));
      __builtin_nontemporal_store(v3, (f4*)(op + 3 * 256));
      f4 p = v0 * q0 + v1 * q1 + v2 * q2 + v3 * q3;
      float d = p.x + p.y + p.z + p.w;
      d = wave_sum64(d);
      // defer-max online softmax (wave-uniform branch; weights bounded by e^8)
      if (d > m + 8.f) {
        float alpha = __expf(m - d);   // m=-inf first iter -> 0
        l *= alpha;
        c0 *= alpha; c1 *= alpha; c2 *= alpha; c3 *= alpha;
        m = d;
      }
      float w = __expf(d - m);
      l += w;
      c0 += w * v0; c1 += w * v1; c2 += w * v2; c3 += w * v3;
      v0 = n0; v1 = n1; v2 = n2; v3 = n3;
    }

    if (lane == 0) { sm[wv] = m; sl[wv] = l; }
    sc[wv][0 * 64 + lane] = c0;
    sc[wv][1 * 64 + lane] = c1;
    sc[wv][2 * 64 + lane] = c2;
    sc[wv][3 * 64 + lane] = c3;
    __syncthreads();

    // combine 16 waves -> one partial per block
    float M = sm[0];
#pragma unroll
    for (int i = 1; i < 16; ++i) M = fmaxf(M, sm[i]);
    if (tid < 256) {
      float wgt[16];
#pragma unroll
      for (int i = 0; i < 16; ++i) wgt[i] = __expf(sm[i] - M);
      f4 a = {0.f, 0.f, 0.f, 0.f};
#pragma unroll
      for (int i = 0; i < 16; ++i) a += wgt[i] * sc[i][tid];
      ((f4*)(pc + (size_t)bid * HID))[tid] = a;
      if (tid == 0) {
        float L = 0.f;
#pragma unroll
        for (int i = 0; i < 16; ++i) L += wgt[i] * sl[i];
        pm[bid] = M;
        pl[bid] = L;
      }
    }
  }
  gbar_arrive(cnt);
  gbar_wait(cnt, NB);

  // ---- P2: reduce 256 partials -> context. Each block owns 4 columns.
  {
    float mi = (tid < NB) ? pm[tid] : -INFINITY;
    float mw = wave_max64(mi);
    if (lane == 0) sred[wv] = mw;
    __syncthreads();
    float M = sred[0];
#pragma unroll
    for (int i = 1; i < 16; ++i) M = fmaxf(M, sred[i]);

    float li = 0.f;
    if (tid < NB) {
      float w = __expf(pm[tid] - M);
      sw[tid] = w;
      li = w * pl[tid];
    }
    float lw = wave_sum64(li);
    __syncthreads();                  // sred reads (M) done
    if (lane == 0) sred[wv] = lw;
    __syncthreads();                  // sw + sred visible
    float L = 0.f;
#pragma unroll
    for (int i = 0; i < 16; ++i) L += sred[i];
    const float invL = 1.f / L;

    const int c = bid * 4 + (tid & 3);
    const int p = tid >> 2;           // 0..255, one load per thread
    sacc[tid] = sw[p] * pc[(size_t)p * HID + c];
    __syncthreads();
    for (int s = 512; s >= 4; s >>= 1) {
      if (tid < s) sacc[tid] += sacc[tid + s];
      __syncthreads();
    }
    if (tid < 4) context[bid * 4 + tid] = sacc[tid] * invL;
  }
  gbar_arrive(cnt);
  gbar_wait(cnt, 2 * NB);

  // ---- P3: h = gelu(W1 @ [u_t|h_s|ctx] + b1). 8 rows/block, 2 waves/row.
  {
    const int row = bid * 8 + (wv >> 1);   // 0..2047
    const int half = wv & 1;
    const float* rp = W1 + (size_t)row * CAT;
    const int s_i = *s_i_p;
    const float* hs = emb + (size_t)s_i * HID;
    float d = 0.f;
#pragma unroll
    for (int j = 0; j < 6; ++j) {
      const int i = half * 6 + j;
      const int k = i * 256 + lane * 4;
      f4 v = *(const f4*)(rp + k);
      const float* src = (i < 4) ? (u_t + k) : (i < 8) ? (hs + k - 1024)
                                                       : (context + k - 2048);
      f4 u = *(const f4*)src;
      f4 p = v * u;
      d += p.x + p.y + p.z + p.w;
    }
    d = wave_sum64(d);
    if (lane == 0) sh[wv] = d;
    __syncthreads();
    if (half == 0 && lane == 0) {
      float x = sh[wv] + sh[wv + 1] + b1[row];
      h[row] = 0.5f * x * (1.0f + erff(x * 0.70710678118654752f));
    }
  }
  gbar_arrive(cnt);
  gbar_wait(cnt, 3 * NB);

  // ---- P4: o = W2 @ h + b2. 4 rows/block, 4 waves/row (512 cols each).
  {
    const int row = bid * 4 + (wv >> 2);   // 0..1023
    const int q = wv & 3;
    const float* rp = W2 + (size_t)row * DUP;
    const int k0 = q * 512 + lane * 4;
    f4 v0 = *(const f4*)(rp + k0);
    f4 u0 = *(const f4*)(h + k0);
    f4 v1 = *(const f4*)(rp + k0 + 256);
    f4 u1 = *(const f4*)(h + k0 + 256);
    f4 p = v0 * u0 + v1 * u1;
    float d = wave_sum64(p.x + p.y + p.z + p.w);
    if (lane == 0) sh[wv] = d;
    __syncthreads();
    if (q == 0 && lane == 0)
      o[row] = sh[wv] + sh[wv + 1] + sh[wv + 2] + sh[wv + 3] + b2[row];
  }
  gbar_arrive(cnt);
  if (bid != 0) return;                    // only block 0 needs P5
  gbar_wait(cnt, 4 * NB);

  // ---- P5: LayerNorm + residual scatter of row s_i. Block 0, 1 float/thread.
  {
    float v = o[tid];
    float s = wave_sum64(v);
    if (lane == 0) sred[wv] = s;
    __syncthreads();
    float mu = 0.f;
#pragma unroll
    for (int i = 0; i < 16; ++i) mu += sred[i];
    mu *= (1.0f / HID);
    float dv = v - mu;
    float q2 = wave_sum64(dv * dv);
    __syncthreads();
    if (lane == 0) sred[wv] = q2;
    __syncthreads();
    float var = 0.f;
#pragma unroll
    for (int i = 0; i < 16; ++i) var += sred[i];
    var *= (1.0f / HID);
    const float inv = rsqrtf(var + LN_EPS);
    const int s_i = *s_i_p;
    out[(size_t)s_i * HID + tid] =
        emb[(size_t)s_i * HID + tid] + dv * inv * gamma[tid] + beta[tid];
  }
}

// ---------------------------------------------------------------------------
extern "C" void kernel_launch(void* const* d_in, const int* in_sizes, int n_in,
                              void* d_out, int out_size, void* d_ws, size_t ws_size,
                              hipStream_t stream) {
  const float* u_t    = (const float*)d_in[0];
  const float* emb    = (const float*)d_in[1];
  const float* W_attn = (const float*)d_in[2];
  const float* W1     = (const float*)d_in[3];
  const float* b1     = (const float*)d_in[4];
  const float* W2     = (const float*)d_in[5];
  const float* b2     = (const float*)d_in[6];
  const float* gamma  = (const float*)d_in[7];
  const float* beta   = (const float*)d_in[8];
  const int*   s_i_p  = (const int*)d_in[9];
  float* out = (float*)d_out;
  float* ws  = (float*)d_ws;

  kA_query<<<256, 256, 0, stream>>>(W_attn, u_t, ws + WS_QUERY,
                                    (int*)(ws + WS_CNT));
  kB_fused<<<NB, 1024, 0, stream>>>(u_t, emb, W1, b1, W2, b2, gamma, beta,
                                    s_i_p, out, ws);
}

// Round 4
// 477.791 us; speedup vs baseline: 1.1529x; 1.1529x over previous
//
#include <hip/hip_runtime.h>
#include <math.h>

// Problem constants
#define NSPK  65536
#define HID   1024
#define DUP   2048
#define CAT   3072
#define LN_EPS 1e-5f

typedef float f4 __attribute__((ext_vector_type(4)));

// K1: 1024 blocks x 512 threads = 8192 waves, 8 rows/wave.
constexpr int K1_NBLK = 1024;

// Workspace layout (floats):
//   query:   [0,    1024)
//   context: [1024, 2048)
//   h:       [2048, 4096)
//   o:       [4096, 5120)
//   pm:      [5120, 6144)
//   pl:      [6144, 7168)
//   pc:      [8192, 8192 + 1024*1024)   (4 MiB)
#define WS_QUERY   0
#define WS_CONTEXT 1024
#define WS_H       2048
#define WS_O       4096
#define WS_PM      5120
#define WS_PL      6144
#define WS_PC      8192

__device__ __forceinline__ float wave_sum64(float d) {
#pragma unroll
  for (int s = 32; s > 0; s >>= 1) d += __shfl_xor(d, s, 64);
  return d;
}
__device__ __forceinline__ float wave_max64(float d) {
#pragma unroll
  for (int s = 32; s > 0; s >>= 1) d = fmaxf(d, __shfl_xor(d, s, 64));
  return d;
}

// ---------------------------------------------------------------------------
// K0: query = W_attn @ u_t.  One wave per output row (1024 rows).
__global__ __launch_bounds__(256) void k0_query(
    const float* __restrict__ W_attn, const float* __restrict__ u_t,
    float* __restrict__ query) {
  const int lane = threadIdx.x & 63;
  const int wv = threadIdx.x >> 6;
  const int row = blockIdx.x * 4 + wv;
  const float* rp = W_attn + (size_t)row * HID;
  float d = 0.f;
#pragma unroll
  for (int i = 0; i < 4; ++i) {
    f4 v = *(const f4*)(rp + i * 256 + lane * 4);
    f4 u = *(const f4*)(u_t + i * 256 + lane * 4);
    f4 p = v * u;
    d += p.x + p.y + p.z + p.w;
  }
  d = wave_sum64(d);
  if (lane == 0) query[row] = d;
}

// ---------------------------------------------------------------------------
// K1: fused pass over the speaker bank (copy + logits + context partials).
// 1024 blocks x 512 threads (8 waves), 8 rows/wave. Validated per-wave body:
// reg double-buffer, NT loads/stores, defer-max online softmax.
__global__ __launch_bounds__(512) void k1_pass(
    const float* __restrict__ emb, const float* __restrict__ query,
    float* __restrict__ out, float* __restrict__ pm, float* __restrict__ pl,
    float* __restrict__ pc) {
  const int tid = threadIdx.x;
  const int lane = tid & 63;
  const int wv = tid >> 6;                    // 0..7
  const int gw = blockIdx.x * 8 + wv;         // 0..8191
  const int col = lane * 4;

  f4 q0 = *(const f4*)(query + 0 * 256 + col);
  f4 q1 = *(const f4*)(query + 1 * 256 + col);
  f4 q2 = *(const f4*)(query + 2 * 256 + col);
  f4 q3 = *(const f4*)(query + 3 * 256 + col);

  float m = -INFINITY, l = 0.f;
  f4 c0 = {0.f, 0.f, 0.f, 0.f}, c1 = c0, c2 = c0, c3 = c0;

  const int row0 = gw * 8;
  const float* rp0 = emb + (size_t)row0 * HID + col;
  f4 v0 = __builtin_nontemporal_load((const f4*)(rp0 + 0 * 256));
  f4 v1 = __builtin_nontemporal_load((const f4*)(rp0 + 1 * 256));
  f4 v2 = __builtin_nontemporal_load((const f4*)(rp0 + 2 * 256));
  f4 v3 = __builtin_nontemporal_load((const f4*)(rp0 + 3 * 256));

  for (int r = 0; r < 8; ++r) {
    f4 n0, n1, n2, n3;
    if (r < 7) {
      const float* np = emb + (size_t)(row0 + r + 1) * HID + col;
      n0 = __builtin_nontemporal_load((const f4*)(np + 0 * 256));
      n1 = __builtin_nontemporal_load((const f4*)(np + 1 * 256));
      n2 = __builtin_nontemporal_load((const f4*)(np + 2 * 256));
      n3 = __builtin_nontemporal_load((const f4*)(np + 3 * 256));
    } else {
      n0 = v0; n1 = v1; n2 = v2; n3 = v3;
    }
    float* op = out + (size_t)(row0 + r) * HID + col;
    __builtin_nontemporal_store(v0, (f4*)(op + 0 * 256));
    __builtin_nontemporal_store(v1, (f4*)(op + 1 * 256));
    __builtin_nontemporal_store(v2, (f4*)(op + 2 * 256));
    __builtin_nontemporal_store(v3, (f4*)(op + 3 * 256));
    f4 p = v0 * q0 + v1 * q1 + v2 * q2 + v3 * q3;
    float d = p.x + p.y + p.z + p.w;
    d = wave_sum64(d);
    // defer-max online softmax (wave-uniform branch; weights bounded by e^8)
    if (d > m + 8.f) {
      float alpha = __expf(m - d);   // m=-inf first iter -> 0
      l *= alpha;
      c0 *= alpha; c1 *= alpha; c2 *= alpha; c3 *= alpha;
      m = d;
    }
    float w = __expf(d - m);
    l += w;
    c0 += w * v0; c1 += w * v1; c2 += w * v2; c3 += w * v3;
    v0 = n0; v1 = n1; v2 = n2; v3 = n3;
  }

  // Block combine across the 8 waves in LDS.
  __shared__ float sm[8], sl[8];
  __shared__ f4 sc[8][256];          // 32 KiB
  if (lane == 0) { sm[wv] = m; sl[wv] = l; }
  sc[wv][0 * 64 + lane] = c0;
  sc[wv][1 * 64 + lane] = c1;
  sc[wv][2 * 64 + lane] = c2;
  sc[wv][3 * 64 + lane] = c3;
  __syncthreads();

  if (tid < 256) {
    float M = sm[0];
#pragma unroll
    for (int i = 1; i < 8; ++i) M = fmaxf(M, sm[i]);
    float wgt[8];
#pragma unroll
    for (int i = 0; i < 8; ++i) wgt[i] = __expf(sm[i] - M);
    f4 a = {0.f, 0.f, 0.f, 0.f};
#pragma unroll
    for (int i = 0; i < 8; ++i) a += wgt[i] * sc[i][tid];
    ((f4*)(pc + (size_t)blockIdx.x * HID))[tid] = a;
    if (tid == 0) {
      float L = 0.f;
#pragma unroll
      for (int i = 0; i < 8; ++i) L += wgt[i] * sl[i];
      pm[blockIdx.x] = M;
      pl[blockIdx.x] = L;
    }
  }
}

// ---------------------------------------------------------------------------
// K2: reduce 1024 block partials -> context[1024].
// 64 blocks x 1024 threads; block b owns 16 consecutive columns (coalesced).
__global__ __launch_bounds__(1024) void k2_reduce(
    const float* __restrict__ pm, const float* __restrict__ pl,
    const float* __restrict__ pc, float* __restrict__ context) {
  __shared__ float sred[16];
  __shared__ float sw[K1_NBLK];      // 4 KiB
  __shared__ float sacc[1024];
  const int tid = threadIdx.x;
  const int lane = tid & 63;
  const int wvi = tid >> 6;          // 0..15

  // global max over 1024 partials (one per thread)
  float mx = wave_max64(pm[tid]);
  if (lane == 0) sred[wvi] = mx;
  __syncthreads();
  float M = sred[0];
#pragma unroll
  for (int i = 1; i < 16; ++i) M = fmaxf(M, sred[i]);

  // exp weights + global denom
  float w = __expf(pm[tid] - M);
  sw[tid] = w;
  float ls = wave_sum64(w * pl[tid]);
  __syncthreads();                   // sred reads (M) done
  if (lane == 0) sred[wvi] = ls;
  __syncthreads();                   // sw + sred visible
  float L = 0.f;
#pragma unroll
  for (int i = 0; i < 16; ++i) L += sred[i];
  const float invL = 1.f / L;

  // 16 consecutive columns per block; p-depth 64 per thread-group.
  const int ci = tid & 15;
  const int p0 = tid >> 4;           // 0..63
  const int c = blockIdx.x * 16 + ci;
  float acc = 0.f;
#pragma unroll 4
  for (int p = p0; p < K1_NBLK; p += 64) acc += sw[p] * pc[(size_t)p * HID + c];
  sacc[tid] = acc;
  __syncthreads();
  for (int s = 32; s >= 1; s >>= 1) {
    if ((tid >> 4) < s) sacc[tid] += sacc[tid + s * 16];
    __syncthreads();
  }
  if (tid < 16) context[blockIdx.x * 16 + tid] = sacc[tid] * invL;
}

// ---------------------------------------------------------------------------
// K3: h = gelu(W1 @ [u_t|h_s|ctx] + b1). 1024 blocks, 2 rows/block,
// 2 waves/row (halves the serial load depth vs 1 wave/row).
__global__ __launch_bounds__(256) void k3_fc1(
    const float* __restrict__ W1, const float* __restrict__ b1,
    const float* __restrict__ u_t, const float* __restrict__ emb,
    const int* __restrict__ s_i_p, const float* __restrict__ context,
    float* __restrict__ h) {
  __shared__ float sh[4];
  const int lane = threadIdx.x & 63;
  const int wv = threadIdx.x >> 6;
  const int row = blockIdx.x * 2 + (wv >> 1);  // 0..2047
  const int half = wv & 1;
  const float* rp = W1 + (size_t)row * CAT;
  const int s_i = *s_i_p;
  const float* hs = emb + (size_t)s_i * HID;
  float d = 0.f;
#pragma unroll
  for (int j = 0; j < 6; ++j) {
    const int i = half * 6 + j;
    const int k = i * 256 + lane * 4;
    f4 v = *(const f4*)(rp + k);
    const float* src = (i < 4) ? (u_t + k) : (i < 8) ? (hs + k - 1024)
                                                     : (context + k - 2048);
    f4 u = *(const f4*)src;
    f4 p = v * u;
    d += p.x + p.y + p.z + p.w;
  }
  d = wave_sum64(d);
  if (lane == 0) sh[wv] = d;
  __syncthreads();
  if (half == 0 && lane == 0) {
    float x = sh[wv] + sh[wv + 1] + b1[row];
    h[row] = 0.5f * x * (1.0f + erff(x * 0.70710678118654752f));
  }
}

// ---------------------------------------------------------------------------
// K4: o = W2 @ h + b2. 512 blocks, 2 rows/block, 2 waves/row.
__global__ __launch_bounds__(256) void k4_fc2(
    const float* __restrict__ W2, const float* __restrict__ b2,
    const float* __restrict__ h, float* __restrict__ o) {
  __shared__ float sh[4];
  const int lane = threadIdx.x & 63;
  const int wv = threadIdx.x >> 6;
  const int row = blockIdx.x * 2 + (wv >> 1);  // 0..1023
  const int half = wv & 1;
  const float* rp = W2 + (size_t)row * DUP;
  const int k0 = half * 1024 + lane * 4;
  f4 v0 = *(const f4*)(rp + k0);
  f4 u0 = *(const f4*)(h + k0);
  f4 v1 = *(const f4*)(rp + k0 + 256);
  f4 u1 = *(const f4*)(h + k0 + 256);
  f4 v2 = *(const f4*)(rp + k0 + 512);
  f4 u2 = *(const f4*)(h + k0 + 512);
  f4 v3 = *(const f4*)(rp + k0 + 768);
  f4 u3 = *(const f4*)(h + k0 + 768);
  f4 p = v0 * u0 + v1 * u1 + v2 * u2 + v3 * u3;
  float d = wave_sum64(p.x + p.y + p.z + p.w);
  if (lane == 0) sh[wv] = d;
  __syncthreads();
  if (half == 0 && lane == 0) o[row] = sh[wv] + sh[wv + 1] + b2[row];
}

// ---------------------------------------------------------------------------
// K5: LayerNorm(o) + residual scatter of row s_i. 1 block x 256 threads.
__global__ __launch_bounds__(256) void k5_ln_scatter(
    const float* __restrict__ o, const float* __restrict__ gamma,
    const float* __restrict__ beta, const float* __restrict__ emb,
    const int* __restrict__ s_i_p, float* __restrict__ out) {
  __shared__ float red[256];
  const int tid = threadIdx.x;
  f4 v = *(const f4*)(o + tid * 4);
  float s = v.x + v.y + v.z + v.w;
  red[tid] = s;
  __syncthreads();
  for (int t = 128; t > 0; t >>= 1) {
    if (tid < t) red[tid] += red[tid + t];
    __syncthreads();
  }
  const float mu = red[0] * (1.0f / HID);
  __syncthreads();
  float dx = v.x - mu, dy = v.y - mu, dz = v.z - mu, dw = v.w - mu;
  red[tid] = dx * dx + dy * dy + dz * dz + dw * dw;
  __syncthreads();
  for (int t = 128; t > 0; t >>= 1) {
    if (tid < t) red[tid] += red[tid + t];
    __syncthreads();
  }
  const float var = red[0] * (1.0f / HID);
  const float inv = rsqrtf(var + LN_EPS);
  const int s_i = *s_i_p;
  const float* hs = emb + (size_t)s_i * HID;
  f4 g = *(const f4*)(gamma + tid * 4);
  f4 b = *(const f4*)(beta + tid * 4);
  f4 hv = *(const f4*)(hs + tid * 4);
  f4 r;
  r.x = hv.x + dx * inv * g.x + b.x;
  r.y = hv.y + dy * inv * g.y + b.y;
  r.z = hv.z + dz * inv * g.z + b.z;
  r.w = hv.w + dw * inv * g.w + b.w;
  *(f4*)(out + (size_t)s_i * HID + tid * 4) = r;
}

// ---------------------------------------------------------------------------
extern "C" void kernel_launch(void* const* d_in, const int* in_sizes, int n_in,
                              void* d_out, int out_size, void* d_ws, size_t ws_size,
                              hipStream_t stream) {
  const float* u_t    = (const float*)d_in[0];
  const float* emb    = (const float*)d_in[1];
  const float* W_attn = (const float*)d_in[2];
  const float* W1     = (const float*)d_in[3];
  const float* b1     = (const float*)d_in[4];
  const float* W2     = (const float*)d_in[5];
  const float* b2     = (const float*)d_in[6];
  const float* gamma  = (const float*)d_in[7];
  const float* beta   = (const float*)d_in[8];
  const int*   s_i_p  = (const int*)d_in[9];
  float* out = (float*)d_out;

  float* ws = (float*)d_ws;
  float* query   = ws + WS_QUERY;
  float* context = ws + WS_CONTEXT;
  float* h       = ws + WS_H;
  float* o       = ws + WS_O;
  float* pm      = ws + WS_PM;
  float* pl      = ws + WS_PL;
  float* pc      = ws + WS_PC;

  k0_query<<<256, 256, 0, stream>>>(W_attn, u_t, query);
  k1_pass<<<K1_NBLK, 512, 0, stream>>>(emb, query, out, pm, pl, pc);
  k2_reduce<<<64, 1024, 0, stream>>>(pm, pl, pc, context);
  k3_fc1<<<1024, 256, 0, stream>>>(W1, b1, u_t, emb, s_i_p, context, h);
  k4_fc2<<<512, 256, 0, stream>>>(W2, b2, h, o);
  k5_ln_scatter<<<1, 256, 0, stream>>>(o, gamma, beta, emb, s_i_p, out);
}